// Round 8
// baseline (1064.327 us; speedup 1.0000x reference)
//
#include <hip/hip_runtime.h>
#include <hip/hip_cooperative_groups.h>
#include <cstddef>

namespace cg = cooperative_groups;

#define BB   256    // batch (GEMM1 M)
#define UU   8      // in_units
#define ISZ  1152   // in_size
#define JJ   10     // out_units
#define DD   16     // out_size
#define JD   (JJ*DD)      // 160
#define K1   (UU*ISZ)     // 9216
#define KS   16           // split-K for sgemm
#define KCH  (K1/KS)      // 576
#define GRID 640

typedef short v8s __attribute__((ext_vector_type(8)));   // 8 bf16 in 4 VGPRs
typedef float f4v __attribute__((ext_vector_type(4)));   // mfma accumulator

__device__ __forceinline__ unsigned short f2bf(float f) {
    unsigned int u = __float_as_uint(f);
    unsigned int r = (u + 0x7fffu + ((u >> 16) & 1u)) >> 16;   // RNE
    return (unsigned short)r;
}
__device__ __forceinline__ float bf2f(unsigned short h) {
    return __uint_as_float(((unsigned int)h) << 16);
}

// ================= monolithic cooperative kernel =================
__global__ __launch_bounds__(256, 3) void capsule_monolith(
        const float* __restrict__ x, const float* __restrict__ W,
        float* __restrict__ v_out,
        float* __restrict__ b_ij, float* __restrict__ s_part,
        unsigned short* __restrict__ xbh, unsigned short* __restrict__ xbl,
        unsigned short* __restrict__ xth, unsigned short* __restrict__ xtl,
        unsigned short* __restrict__ bth, unsigned short* __restrict__ btl,
        unsigned short* __restrict__ vth, unsigned short* __restrict__ vtl) {
    cg::grid_group gg = cg::this_grid();
    int bid = blockIdx.x;
    int t = threadIdx.x;
    int lane = t & 63, wv = t >> 6;

    __shared__ float tile[64][65];
    __shared__ float redm[4], reds[4];
    __shared__ float sm[JD];

    // ---- P0: prep (x -> bf16-split row-major and transposed) + b_ij = 1 ----
    if (bid < 45) b_ij[bid * 256 + t] = 1.0f;
    if (bid < 576) {
        int kt = bid % 144, bt = bid / 144;
        int k0 = kt * 64, b0 = bt * 64;
#pragma unroll
        for (int r = 0; r < 16; ++r) {
            int br = wv * 16 + r;
            float v = x[(size_t)(b0 + br) * K1 + k0 + lane];
            tile[br][lane] = v;
            unsigned short h = f2bf(v);
            size_t o = (size_t)(b0 + br) * K1 + k0 + lane;
            xbh[o] = h; xbl[o] = f2bf(v - bf2f(h));
        }
        __syncthreads();
#pragma unroll
        for (int r = 0; r < 16; ++r) {
            int kr = wv * 16 + r;
            float v = tile[lane][kr];
            unsigned short h = f2bf(v);
            size_t o = (size_t)(k0 + kr) * BB + b0 + lane;
            xth[o] = h; xtl[o] = f2bf(v - bf2f(h));
        }
    }
    gg.sync();

    for (int it = 0; it < 3; ++it) {
        // ---- P1: build B^T[(j,d)][(u,i)] = bf16split(c[i,j]*W), fused softmax ----
        if (bid < JD) {
            int jd = bid, j = jd >> 4;
            float m = 0.f, inv = 1.0f / 1152.0f;
            if (it != 0) {
                const float* bp = b_ij + (size_t)j * ISZ;
                m = -1e30f;
                for (int k = t; k < ISZ; k += 256) m = fmaxf(m, bp[k]);
#pragma unroll
                for (int off = 32; off; off >>= 1) m = fmaxf(m, __shfl_down(m, off, 64));
                if (lane == 0) redm[wv] = m;
                __syncthreads();
                m = fmaxf(fmaxf(redm[0], redm[1]), fmaxf(redm[2], redm[3]));
                float ss = 0.f;
                for (int k = t; k < ISZ; k += 256) ss += __expf(bp[k] - m);
#pragma unroll
                for (int off = 32; off; off >>= 1) ss += __shfl_down(ss, off, 64);
                if (lane == 0) reds[wv] = ss;
                __syncthreads();
                inv = 1.f / (reds[0] + reds[1] + reds[2] + reds[3]);
            }
            for (int i = t; i < ISZ; i += 256) {
                float ci = (it == 0) ? inv
                         : __expf(b_ij[(size_t)j * ISZ + i] - m) * inv;
                const float* Wp = W + (size_t)i * (JD * UU) + jd * UU;
#pragma unroll
                for (int u = 0; u < 8; ++u) {
                    float val = ci * Wp[u];
                    unsigned short h = f2bf(val);
                    size_t o = (size_t)jd * K1 + (size_t)u * ISZ + i;
                    bth[o] = h; btl[o] = f2bf(val - bf2f(h));
                }
            }
        }
        gg.sync();

        // ---- P2: split-K GEMM  s_part[ks][b][jd] = x @ B ----
        {
            int bx = bid & 3, j = (bid >> 2) % 10, ks = bid / 40;
            int mt = bx * 4 + wv;
            int m0 = mt * 16, n0 = j * 16;
            int col = lane & 15, q = lane >> 4;
            size_t aoff = (size_t)(m0 + col) * K1 + ks * KCH + q * 8;
            size_t boff = (size_t)(n0 + col) * K1 + ks * KCH + q * 8;
            f4v acc = {0.f, 0.f, 0.f, 0.f};
#pragma unroll
            for (int s = 0; s < KCH / 32; ++s) {
                v8s ah = *(const v8s*)(xbh + aoff);
                v8s al = *(const v8s*)(xbl + aoff);
                v8s bh = *(const v8s*)(bth + boff);
                v8s bl = *(const v8s*)(btl + boff);
                acc = __builtin_amdgcn_mfma_f32_16x16x32_bf16(ah, bh, acc, 0, 0, 0);
                acc = __builtin_amdgcn_mfma_f32_16x16x32_bf16(ah, bl, acc, 0, 0, 0);
                acc = __builtin_amdgcn_mfma_f32_16x16x32_bf16(al, bh, acc, 0, 0, 0);
                aoff += 32; boff += 32;
            }
#pragma unroll
            for (int r = 0; r < 4; ++r)
                s_part[((size_t)ks * BB + m0 + q * 4 + r) * JD + n0 + col] = acc[r];
        }
        gg.sync();

        // ---- P3: reduce split-K + squash; v -> d_out, vT bf16-split ----
        if (bid < BB) {
            int b = bid;
            float s = 0.f;
            if (t < JD) {
#pragma unroll
                for (int ks = 0; ks < KS; ++ks) s += s_part[((size_t)ks * BB + b) * JD + t];
                sm[t] = s;
            }
            __syncthreads();
            if (t < JD) {
                int d = t & 15;
                float msq = 0.f;
#pragma unroll
                for (int j = 0; j < JJ; ++j) { float xx = sm[j * DD + d]; msq += xx * xx; }
                float val = msq / (1.f + msq) * s * rsqrtf(msq);
                v_out[(size_t)b * JD + t] = val;
                unsigned short h = f2bf(val);
                vth[(size_t)t * BB + b] = h;
                vtl[(size_t)t * BB + b] = f2bf(val - bf2f(h));
            }
        }

        if (it < 2) {
            gg.sync();
            // ---- P4: mGEMM (vT @ x, K=256) + fused agreement epilogue ----
            int gw = bid * 4 + wv;            // 2560 waves, 5760 wave-jobs
            for (int wj = gw; wj < 5760; wj += GRID * 4) {
                int mt = wj / 576;            // j
                int nt = wj % 576;
                int m0 = mt * 16, n0 = nt * 16;
                int col = lane & 15, q = lane >> 4;
                size_t aoff = (size_t)(m0 + col) * BB + q * 8;
                size_t boff = (size_t)(n0 + col) * BB + q * 8;
                f4v acc = {0.f, 0.f, 0.f, 0.f};
#pragma unroll
                for (int s = 0; s < BB / 32; ++s) {
                    v8s ah = *(const v8s*)(vth + aoff);
                    v8s al = *(const v8s*)(vtl + aoff);
                    v8s bh = *(const v8s*)(xth + boff);
                    v8s bl = *(const v8s*)(xtl + boff);
                    acc = __builtin_amdgcn_mfma_f32_16x16x32_bf16(ah, bh, acc, 0, 0, 0);
                    acc = __builtin_amdgcn_mfma_f32_16x16x32_bf16(ah, bl, acc, 0, 0, 0);
                    acc = __builtin_amdgcn_mfma_f32_16x16x32_bf16(al, bh, acc, 0, 0, 0);
                    aoff += 32; boff += 32;
                }
                // acc[r] = M[j*16 + (q*4+r)][k1=n0+col]; fold into b_ij
                int u = nt / 72;
                int i = (nt % 72) * 16 + col;
                const float* Wp = W + (size_t)i * (JD * UU) + mt * (DD * UU) + q * 32 + u;
                float p = Wp[0] * acc[0] + Wp[8] * acc[1] + Wp[16] * acc[2] + Wp[24] * acc[3];
                p += __shfl_xor(p, 16, 64);
                p += __shfl_xor(p, 32, 64);
                if (q == 0) atomicAdd(&b_ij[(size_t)mt * ISZ + i], p * (1.0f / 256.0f));
            }
            gg.sync();
        }
    }
}

// ================= fallback multi-launch path (R7-proven) =================
__global__ void prep_kernel(const float* __restrict__ x,
                            unsigned short* __restrict__ xbh, unsigned short* __restrict__ xbl,
                            unsigned short* __restrict__ xth, unsigned short* __restrict__ xtl,
                            float* __restrict__ b_ij) {
    __shared__ float tile[64][65];
    int kt = blockIdx.x, bt = blockIdx.y;
    int k0 = kt * 64, b0 = bt * 64;
    int t = threadIdx.x, lane = t & 63, wv = t >> 6;
    int flat = blockIdx.y * 144 + blockIdx.x;
    if (flat < 45) b_ij[flat * 256 + t] = 1.0f;
#pragma unroll
    for (int r = 0; r < 16; ++r) {
        int br = wv * 16 + r;
        float v = x[(size_t)(b0 + br) * K1 + k0 + lane];
        tile[br][lane] = v;
        unsigned short h = f2bf(v);
        size_t o = (size_t)(b0 + br) * K1 + k0 + lane;
        xbh[o] = h; xbl[o] = f2bf(v - bf2f(h));
    }
    __syncthreads();
#pragma unroll
    for (int r = 0; r < 16; ++r) {
        int kr = wv * 16 + r;
        float v = tile[lane][kr];
        unsigned short h = f2bf(v);
        size_t o = (size_t)(k0 + kr) * BB + b0 + lane;
        xth[o] = h; xtl[o] = f2bf(v - bf2f(h));
    }
}

__global__ void build_b_kernel(const float* __restrict__ W, const float* __restrict__ b_ij,
                               unsigned short* __restrict__ bth, unsigned short* __restrict__ btl,
                               int first) {
    int jd = blockIdx.x, j = jd >> 4;
    int t = threadIdx.x, lane = t & 63, wv = t >> 6;
    __shared__ float rm[3], rs[3];
    float m = 0.f, inv = 1.0f / 1152.0f;
    if (!first) {
        const float* bp = b_ij + (size_t)j * ISZ;
        m = -1e30f;
        for (int k = t; k < ISZ; k += 192) m = fmaxf(m, bp[k]);
#pragma unroll
        for (int off = 32; off; off >>= 1) m = fmaxf(m, __shfl_down(m, off, 64));
        if (lane == 0) rm[wv] = m;
        __syncthreads();
        m = fmaxf(fmaxf(rm[0], rm[1]), rm[2]);
        float ss = 0.f;
        for (int k = t; k < ISZ; k += 192) ss += __expf(bp[k] - m);
#pragma unroll
        for (int off = 32; off; off >>= 1) ss += __shfl_down(ss, off, 64);
        if (lane == 0) rs[wv] = ss;
        __syncthreads();
        inv = 1.f / (rs[0] + rs[1] + rs[2]);
    }
    for (int ch = 0; ch < 6; ++ch) {
        int i = ch * 192 + t;
        float ci = first ? inv : __expf(b_ij[(size_t)j * ISZ + i] - m) * inv;
        const float* Wp = W + (size_t)i * (JD * UU) + jd * UU;
#pragma unroll
        for (int u = 0; u < 8; ++u) {
            float val = ci * Wp[u];
            unsigned short h = f2bf(val);
            size_t o = (size_t)jd * K1 + (size_t)u * ISZ + i;
            bth[o] = h; btl[o] = f2bf(val - bf2f(h));
        }
    }
}

__global__ __launch_bounds__(256) void sgemm_kernel(
        const unsigned short* __restrict__ Ah, const unsigned short* __restrict__ Al,
        const unsigned short* __restrict__ Bh, const unsigned short* __restrict__ Bl,
        float* __restrict__ s_part) {
    int w = threadIdx.x >> 6, lane = threadIdx.x & 63;
    int mt = blockIdx.x * 4 + w, nt = blockIdx.y, ks = blockIdx.z;
    int m0 = mt * 16, n0 = nt * 16;
    int col = lane & 15, q = lane >> 4;
    size_t aoff = (size_t)(m0 + col) * K1 + ks * KCH + q * 8;
    size_t boff = (size_t)(n0 + col) * K1 + ks * KCH + q * 8;
    f4v acc = {0.f, 0.f, 0.f, 0.f};
#pragma unroll
    for (int s = 0; s < KCH / 32; ++s) {
        v8s ah = *(const v8s*)(Ah + aoff);
        v8s al = *(const v8s*)(Al + aoff);
        v8s bh = *(const v8s*)(Bh + boff);
        v8s bl = *(const v8s*)(Bl + boff);
        acc = __builtin_amdgcn_mfma_f32_16x16x32_bf16(ah, bh, acc, 0, 0, 0);
        acc = __builtin_amdgcn_mfma_f32_16x16x32_bf16(ah, bl, acc, 0, 0, 0);
        acc = __builtin_amdgcn_mfma_f32_16x16x32_bf16(al, bh, acc, 0, 0, 0);
        aoff += 32; boff += 32;
    }
#pragma unroll
    for (int r = 0; r < 4; ++r)
        s_part[((size_t)ks * BB + m0 + q * 4 + r) * JD + n0 + col] = acc[r];
}

__global__ void reduce_squash_kernel(const float* __restrict__ s_part,
                                     float* __restrict__ v,
                                     unsigned short* __restrict__ vth,
                                     unsigned short* __restrict__ vtl) {
    int b = blockIdx.x, t = threadIdx.x;
    __shared__ float sm[JD];
    float s = 0.f;
    if (t < JD) {
#pragma unroll
        for (int ks = 0; ks < KS; ++ks) s += s_part[((size_t)ks * BB + b) * JD + t];
        sm[t] = s;
    }
    __syncthreads();
    if (t < JD) {
        int d = t & 15;
        float msq = 0.f;
#pragma unroll
        for (int j = 0; j < JJ; ++j) { float xx = sm[j * DD + d]; msq += xx * xx; }
        float val = msq / (1.f + msq) * s * rsqrtf(msq);
        v[(size_t)b * JD + t] = val;
        unsigned short h = f2bf(val);
        vth[(size_t)t * BB + b] = h;
        vtl[(size_t)t * BB + b] = f2bf(val - bf2f(h));
    }
}

__global__ __launch_bounds__(256) void mgemm_agree_kernel(
        const unsigned short* __restrict__ Ah, const unsigned short* __restrict__ Al,
        const unsigned short* __restrict__ Bh, const unsigned short* __restrict__ Bl,
        const float* __restrict__ W, float* __restrict__ b_ij) {
    int w = threadIdx.x >> 6, lane = threadIdx.x & 63;
    int wj = (blockIdx.x * 4 + w);
    int mt = wj / 576, nt = wj % 576;
    int m0 = mt * 16, n0 = nt * 16;
    int col = lane & 15, q = lane >> 4;
    size_t aoff = (size_t)(m0 + col) * BB + q * 8;
    size_t boff = (size_t)(n0 + col) * BB + q * 8;
    f4v acc = {0.f, 0.f, 0.f, 0.f};
#pragma unroll
    for (int s = 0; s < BB / 32; ++s) {
        v8s ah = *(const v8s*)(Ah + aoff);
        v8s al = *(const v8s*)(Al + aoff);
        v8s bh = *(const v8s*)(Bh + boff);
        v8s bl = *(const v8s*)(Bl + boff);
        acc = __builtin_amdgcn_mfma_f32_16x16x32_bf16(ah, bh, acc, 0, 0, 0);
        acc = __builtin_amdgcn_mfma_f32_16x16x32_bf16(ah, bl, acc, 0, 0, 0);
        acc = __builtin_amdgcn_mfma_f32_16x16x32_bf16(al, bh, acc, 0, 0, 0);
        aoff += 32; boff += 32;
    }
    int u = nt / 72;
    int i = (nt % 72) * 16 + col;
    const float* Wp = W + (size_t)i * (JD * UU) + mt * (DD * UU) + q * 32 + u;
    float p = Wp[0] * acc[0] + Wp[8] * acc[1] + Wp[16] * acc[2] + Wp[24] * acc[3];
    p += __shfl_xor(p, 16, 64);
    p += __shfl_xor(p, 32, 64);
    if (q == 0) atomicAdd(&b_ij[(size_t)mt * ISZ + i], p * (1.0f / 256.0f));
}

// ================= launch =================
extern "C" void kernel_launch(void* const* d_in, const int* in_sizes, int n_in,
                              void* d_out, int out_size, void* d_ws, size_t ws_size,
                              hipStream_t stream) {
    const float* x = (const float*)d_in[0];   // (256, 8, 1152)
    const float* W = (const float*)d_in[1];   // (1, 1152, 10, 16, 8)
    float* v_out = (float*)d_out;             // (256, 10, 16, 1)

    float* b_ij   = (float*)d_ws;                          // 11,520 f
    float* s_part = b_ij + ISZ * JJ;                       // 655,360 f
    unsigned short* xbh = (unsigned short*)(s_part + (size_t)KS * BB * JD);
    unsigned short* xbl = xbh + (size_t)BB * K1;
    unsigned short* xth = xbl + (size_t)BB * K1;
    unsigned short* xtl = xth + (size_t)BB * K1;
    unsigned short* bth = xtl + (size_t)BB * K1;
    unsigned short* btl = bth + (size_t)JD * K1;
    unsigned short* vth = btl + (size_t)JD * K1;
    unsigned short* vtl = vth + (size_t)JD * BB;

    void* args[] = { (void*)&x, (void*)&W, (void*)&v_out,
                     (void*)&b_ij, (void*)&s_part,
                     (void*)&xbh, (void*)&xbl, (void*)&xth, (void*)&xtl,
                     (void*)&bth, (void*)&btl, (void*)&vth, (void*)&vtl };
    hipError_t err = hipLaunchCooperativeKernel((void*)capsule_monolith,
                                                dim3(GRID), dim3(256), args, 0, stream);
    if (err != hipSuccess) {
        // fallback: multi-launch pipeline (identical math)
        hipLaunchKernelGGL(prep_kernel, dim3(144, 4), dim3(256), 0, stream,
                           x, xbh, xbl, xth, xtl, b_ij);
        for (int it = 0; it < 3; ++it) {
            hipLaunchKernelGGL(build_b_kernel, dim3(JD), dim3(192), 0, stream,
                               W, b_ij, bth, btl, it == 0 ? 1 : 0);
            hipLaunchKernelGGL(sgemm_kernel, dim3(4, 10, KS), dim3(256), 0, stream,
                               xbh, xbl, bth, btl, s_part);
            hipLaunchKernelGGL(reduce_squash_kernel, dim3(BB), dim3(192), 0, stream,
                               s_part, v_out, vth, vtl);
            if (it < 2) {
                hipLaunchKernelGGL(mgemm_agree_kernel, dim3(1440), dim3(256), 0, stream,
                                   vth, vtl, xth, xtl, W, b_ij);
            }
        }
    }
}